// Round 3
// baseline (292.514 us; speedup 1.0000x reference)
//
#include <hip/hip_runtime.h>
#include <hip/hip_bf16.h>

#define NB 16
#define DMODEL 1024
#define HALFD 512
#define PNUM 4096
#define PLEN 32
#define SEQ 2048
#define SIM 64
#define NPATCH 64
#define NROWS (NB*SEQ)        // 32768 sequence rows
#define MROWS (NB*NPATCH)     // 1024 (b,p) rows
#define KDIM (PLEN*HALFD)     // 16384
#define KSPLIT 8
#define MTILES 16
#define OUT0 ((size_t)NB*SEQ*DMODEL)

// ---------------- K0: gp_w row means + gp_b mean (fp64) ----------------
__global__ void k_prep(const float* __restrict__ gp_w, const float* __restrict__ gp_b,
                       double* __restrict__ gpw_mean) {
    int h = threadIdx.x;                       // 512 threads
    double s = 0.0;
    #pragma unroll
    for (int j = 0; j < 10; ++j) s += (double)gp_w[h*10 + j];
    gpw_mean[h] = s / 10.0;
    if (h == 0) {
        double sb = 0.0;
        #pragma unroll
        for (int j = 0; j < 10; ++j) sb += (double)gp_b[j];
        gpw_mean[HALFD] = sb / 10.0;           // gpb_mean at [512]
    }
}

// ---------------- K1: copy first half + low dot (fp64 accumulate) ----------------
__global__ __launch_bounds__(256) void k_copy_low(
        const float* __restrict__ src, const double* __restrict__ gpw_mean,
        float* __restrict__ out, double* __restrict__ low) {
    int wave = (blockIdx.x * 256 + threadIdx.x) >> 6;   // one wave per row
    int lane = threadIdx.x & 63;
    const float4* s4 = reinterpret_cast<const float4*>(src + (size_t)wave * DMODEL);
    float4 c0 = s4[lane];
    float4 c1 = s4[lane + 64];
    float4* o4 = reinterpret_cast<float4*>(out + (size_t)wave * DMODEL);
    o4[lane]      = c0;
    o4[lane + 64] = c1;
    // low = dot(second half, gpw_mean) + gpb_mean   -- fp64
    float4 x0 = s4[128 + lane];
    float4 x1 = s4[192 + lane];
    const double* g0 = gpw_mean + lane*4;
    const double* g1 = gpw_mean + 256 + lane*4;
    double d = (double)x0.x*g0[0] + (double)x0.y*g0[1] + (double)x0.z*g0[2] + (double)x0.w*g0[3]
             + (double)x1.x*g1[0] + (double)x1.y*g1[1] + (double)x1.z*g1[2] + (double)x1.w*g1[3];
    #pragma unroll
    for (int o = 32; o; o >>= 1) d += __shfl_xor(d, o);
    if (lane == 0) low[wave] = d + gpw_mean[HALFD];
}

// ---------------- K2: scores (batch 0, fp64) + iterative top-64 per patch ----------------
__global__ __launch_bounds__(256) void k_topk(
        const double* __restrict__ low, const float* __restrict__ pool,
        int* __restrict__ sel) {
    __shared__ double sc[PNUM];
    __shared__ double lowp[PLEN];
    __shared__ double rv[256];
    __shared__ int    ri[256];
    int p = blockIdx.x, t = threadIdx.x;
    if (t < PLEN) lowp[t] = low[p*PLEN + t];           // batch 0 rows
    __syncthreads();
    for (int n = t; n < PNUM; n += 256) {
        const float4* p4 = reinterpret_cast<const float4*>(pool + (size_t)n*PLEN);
        double s = 0.0;
        #pragma unroll
        for (int j = 0; j < 8; ++j) {
            float4 v = p4[j];
            s += (double)v.x*lowp[j*4] + (double)v.y*lowp[j*4+1]
               + (double)v.z*lowp[j*4+2] + (double)v.w*lowp[j*4+3];
        }
        sc[n] = s;
    }
    __syncthreads();
    for (int s = 0; s < SIM; ++s) {
        double bv = -1e300; int bi = 0x7fffffff;
        for (int n = t; n < PNUM; n += 256) {
            double v = sc[n];
            if (v > bv) { bv = v; bi = n; }            // increasing n: lowest idx on ties
        }
        rv[t] = bv; ri[t] = bi;
        __syncthreads();
        for (int off = 128; off; off >>= 1) {
            if (t < off) {
                double ov = rv[t+off]; int oi = ri[t+off];
                if (ov > rv[t] || (ov == rv[t] && oi < ri[t])) { rv[t] = ov; ri[t] = oi; }
            }
            __syncthreads();
        }
        if (t == 0) { sel[p*SIM + s] = ri[0]; sc[ri[0]] = -1e300; }
        __syncthreads();
    }
}

// ---------------- K3: logits GEMM partials (M=1024,K=16384,N=64), K-split x8 ----------------
__global__ __launch_bounds__(256) void k_logits(
        const float* __restrict__ src, const float* __restrict__ fw,
        float* __restrict__ part) {
    __shared__ float xs[64][68];
    __shared__ float wsm[64][68];
    int mt = blockIdx.x, ks = blockIdx.y;
    int t = threadIdx.x;
    int r0 = mt * 64;
    int ty = t >> 4, tx = t & 15;
    float acc[4][4] = {};
    for (int kc = 0; kc < KDIM/KSPLIT; kc += 64) {
        int k0 = ks * (KDIM/KSPLIT) + kc;
        int l = k0 >> 9, h0 = k0 & 511;                // 64-chunk never crosses l boundary
        {   // x tile
            int i = t >> 2;
            int row = r0 + i;
            int b = row >> 6, p = row & 63;
            const float* srow = src + ((size_t)(b*SEQ + p*PLEN + l)) * DMODEL + HALFD + h0;
            #pragma unroll
            for (int q = 0; q < 4; ++q) {
                int f4 = (t & 3) + q*4;
                float4 v = *reinterpret_cast<const float4*>(srow + f4*4);
                *reinterpret_cast<float4*>(&xs[i][f4*4]) = v;
            }
        }
        {   // w tile
            int j = t >> 2;
            const float* wrow = fw + (size_t)(k0 + j) * SIM;
            #pragma unroll
            for (int q = 0; q < 4; ++q) {
                int f4 = (t & 3) + q*4;
                float4 v = *reinterpret_cast<const float4*>(wrow + f4*4);
                *reinterpret_cast<float4*>(&wsm[j][f4*4]) = v;
            }
        }
        __syncthreads();
        #pragma unroll 8
        for (int k = 0; k < 64; ++k) {
            float4 wv = *reinterpret_cast<float4*>(&wsm[k][tx*4]);
            #pragma unroll
            for (int i = 0; i < 4; ++i) {
                float a = xs[ty*4 + i][k];
                acc[i][0] += a*wv.x; acc[i][1] += a*wv.y;
                acc[i][2] += a*wv.z; acc[i][3] += a*wv.w;
            }
        }
        __syncthreads();
    }
    float* pp = part + ((size_t)(mt*KSPLIT + ks)) * 4096;
    #pragma unroll
    for (int i = 0; i < 4; ++i) {
        float4 v = { acc[i][0], acc[i][1], acc[i][2], acc[i][3] };
        *reinterpret_cast<float4*>(pp + (ty*4 + i)*64 + tx*4) = v;
    }
}

// ---------------- K4: reduce partials + bias + softmax -> route ----------------
__global__ __launch_bounds__(64) void k_softmax(
        const float* __restrict__ part, const float* __restrict__ fb,
        float* __restrict__ route) {
    int row = blockIdx.x;             // b*64+p
    int s = threadIdx.x;              // 0..63
    int mt = row >> 6, i = row & 63;
    float v = fb[s];
    #pragma unroll
    for (int ks = 0; ks < KSPLIT; ++ks)
        v += part[((size_t)(mt*KSPLIT + ks))*4096 + i*64 + s];
    float m = v;
    #pragma unroll
    for (int o = 32; o; o >>= 1) m = fmaxf(m, __shfl_xor(m, o));
    float e = expf(v - m);
    float sum = e;
    #pragma unroll
    for (int o = 32; o; o >>= 1) sum += __shfl_xor(sum, o);
    route[row*64 + s] = e / sum;
}

// ---------------- K5: fuse + recover GEMM + padding + zeros ----------------
__global__ __launch_bounds__(256) void k_out(
        const float* __restrict__ route, const int* __restrict__ sel,
        const float* __restrict__ pool, const float* __restrict__ rw,
        const float* __restrict__ rb, float* __restrict__ out, float* __restrict__ pad) {
    __shared__ float A[PLEN][SIM + 1];       // [32][65]
    __shared__ float rws[64][132];           // 128-col chunk of recover_w (+pad)
    __shared__ float routeS[64];
    int row = blockIdx.x;                    // b*64+p
    int b = row >> 6, p = row & 63;
    int t = threadIdx.x;
    if (t < 64) routeS[t] = route[row*64 + t];
    __syncthreads();
    #pragma unroll
    for (int q = 0; q < 8; ++q) {            // A[l][s] = route[s]*pool[sel[p,s]][l]
        int e = t + q*256;
        int s = e >> 5, l = e & 31;
        A[l][s] = routeS[s] * pool[(size_t)sel[p*SIM + s]*PLEN + l];
    }
    __syncthreads();
    if (t < 32) {                            // padding row-sum
        float ps = 0.f;
        #pragma unroll
        for (int s = 0; s < 64; ++s) ps += A[t][s];
        pad[(size_t)b*2*SEQ + SEQ + p*PLEN + t] = ps;
    } else if (t < 64) {                     // zeros in first half of padding_out
        pad[(size_t)b*2*SEQ + p*PLEN + (t - 32)] = 0.f;
    }
    int l0  = (t >> 5) * 4;
    int h04 = (t & 31) * 4;
    for (int hc = 0; hc < HALFD; hc += 128) {
        #pragma unroll
        for (int q = 0; q < 8; ++q) {        // stage recover_w[:, hc:hc+128]
            int fi = t + q*256;
            int r = fi >> 5, c4 = fi & 31;
            float4 v = *reinterpret_cast<const float4*>(rw + (size_t)r*HALFD + hc + c4*4);
            *reinterpret_cast<float4*>(&rws[r][c4*4]) = v;
        }
        __syncthreads();
        float acc[4][4] = {};
        #pragma unroll 8
        for (int s = 0; s < 64; ++s) {
            float4 wv = *reinterpret_cast<float4*>(&rws[s][h04]);
            #pragma unroll
            for (int i = 0; i < 4; ++i) {
                float a = A[l0 + i][s];
                acc[i][0] += a*wv.x; acc[i][1] += a*wv.y;
                acc[i][2] += a*wv.z; acc[i][3] += a*wv.w;
            }
        }
        int h = hc + h04;
        float4 bias = *reinterpret_cast<const float4*>(rb + h);
        #pragma unroll
        for (int i = 0; i < 4; ++i) {
            int l = l0 + i;
            float4 v = { acc[i][0] + bias.x, acc[i][1] + bias.y,
                         acc[i][2] + bias.z, acc[i][3] + bias.w };
            *reinterpret_cast<float4*>(out + ((size_t)(b*SEQ + p*PLEN + l))*DMODEL + HALFD + h) = v;
        }
        __syncthreads();
    }
}

static const void* by_size(void* const* d_in, const int* in_sizes, int n_in,
                           int want, int fallback) {
    for (int i = 0; i < n_in; ++i) if (in_sizes[i] == want) return d_in[i];
    return d_in[fallback];
}

extern "C" void kernel_launch(void* const* d_in, const int* in_sizes, int n_in,
                              void* d_out, int out_size, void* d_ws, size_t ws_size,
                              hipStream_t stream) {
    const float* src  = (const float*)by_size(d_in, in_sizes, n_in, NB*SEQ*DMODEL, 0);
    const float* pool = (const float*)by_size(d_in, in_sizes, n_in, PNUM*PLEN, 1);
    const float* fw   = (const float*)by_size(d_in, in_sizes, n_in, KDIM*SIM, 2);
    const float* fb   = (const float*)by_size(d_in, in_sizes, n_in, SIM, 3);
    const float* rw   = (const float*)by_size(d_in, in_sizes, n_in, SIM*HALFD, 4);
    const float* rb   = (const float*)by_size(d_in, in_sizes, n_in, HALFD, 5);
    const float* gpw  = (const float*)by_size(d_in, in_sizes, n_in, HALFD*10, 6);
    const float* gpb  = (const float*)by_size(d_in, in_sizes, n_in, 10, 7);
    float* out = (float*)d_out;
    float* pad = out + OUT0;

    double* gpw_mean = (double*)d_ws;                       // 513 doubles (pad to 1024)
    double* low      = gpw_mean + 1024;                     // 32768 doubles
    int*    sel      = (int*)(low + 32768);                 // 4096 ints
    float*  part     = (float*)(sel + 4096);                // 16*8*4096 floats = 2MB
    float*  route    = part + (size_t)MTILES*KSPLIT*4096;   // 65536 floats

    hipLaunchKernelGGL(k_prep,     dim3(1),          dim3(512), 0, stream, gpw, gpb, gpw_mean);
    hipLaunchKernelGGL(k_copy_low, dim3(NROWS/4),    dim3(256), 0, stream, src, gpw_mean, out, low);
    hipLaunchKernelGGL(k_topk,     dim3(NPATCH),     dim3(256), 0, stream, low, pool, sel);
    hipLaunchKernelGGL(k_logits,   dim3(MTILES, KSPLIT), dim3(256), 0, stream, src, fw, part);
    hipLaunchKernelGGL(k_softmax,  dim3(MROWS),      dim3(64),  0, stream, part, fb, route);
    hipLaunchKernelGGL(k_out,      dim3(MROWS),      dim3(256), 0, stream, route, sel, pool, rw, rb, out, pad);
}